// Round 4
// baseline (655.956 us; speedup 1.0000x reference)
//
#include <hip/hip_runtime.h>

#define NN 12288
#define DD 128
#define NG 48

typedef float v4f __attribute__((ext_vector_type(4)));

// ---------------------------------------------------------------------------
// Kernel A: graph boundary table start[0..NG] (lower bounds) in workspace.
// batch[] is sorted; boundaries are where batch[j] != batch[j-1].
// ---------------------------------------------------------------------------
__global__ __launch_bounds__(256) void build_starts(
    const int* __restrict__ batch, int* __restrict__ start)
{
    for (int j = threadIdx.x; j <= NN; j += 256) {
        if (j == NN) {
            const int b = batch[NN - 1];
            for (int g = b + 1; g <= NG; ++g) start[g] = NN;
        } else {
            const int b = batch[j];
            const int bprev = (j == 0) ? -1 : batch[j - 1];
            for (int g = bprev + 1; g <= b; ++g) start[g] = j;
        }
    }
}

// ---------------------------------------------------------------------------
// Kernel B: write ONLY the nonzero cells, on top of the hipMemsetAsync zeros.
// One wave per row. Row i scans its same-graph band [lo,hi); for each column
// with matching class (and j != i) it computes the 128-dim dot and stores the
// single scalar. ~117K stores (~0.5 MB) + ~60 MFLOP total: latency-trivial.
// fmaf chain order identical to R0-R3 -> bit-exact (absmax must stay 0.0).
// Runs after the memset on the same stream => ordered, race-free.
// ---------------------------------------------------------------------------
__global__ __launch_bounds__(64) void band_fill(
    const float* __restrict__ z1, const float* __restrict__ z2,
    const int* __restrict__ cls, const int* __restrict__ batch,
    const int* __restrict__ start, float* __restrict__ out)
{
    const int i = (int)blockIdx.x;
    const int cls_i = cls[i];
    if (cls_i >= 24) return;                  // excluded class: row stays zero

    const int b  = batch[i];
    const int lo = start[b];
    const int hi = start[b + 1];

    const v4f* __restrict__ za = reinterpret_cast<const v4f*>(z1 + (size_t)i * DD);
    float* __restrict__ orow = out + (size_t)i * NN;

    for (int j = lo + (int)threadIdx.x; j < hi; j += 64) {
        if (j != i && cls[j] == cls_i) {
            const v4f* __restrict__ zb =
                reinterpret_cast<const v4f*>(z2 + (size_t)j * DD);
            float s = 0.f;
            #pragma unroll
            for (int d = 0; d < DD / 4; ++d) {
                const v4f a  = za[d];
                const v4f b4 = zb[d];
                s = fmaf(a.x, b4.x, s);
                s = fmaf(a.y, b4.y, s);
                s = fmaf(a.z, b4.z, s);
                s = fmaf(a.w, b4.w, s);
            }
            orow[j] = s;
        }
    }
}

extern "C" void kernel_launch(void* const* d_in, const int* in_sizes, int n_in,
                              void* d_out, int out_size, void* d_ws, size_t ws_size,
                              hipStream_t stream) {
    const float* z1    = (const float*)d_in[0];
    const float* z2    = (const float*)d_in[1];
    const int*   cls   = (const int*)d_in[2];
    const int*   batch = (const int*)d_in[3];
    float*       out   = (float*)d_out;
    int*         start = (int*)d_ws;           // needs 49 ints

    // Vendor fill path (the 6.2 TB/s fillBufferAligned) zeroes the output.
    hipMemsetAsync(out, 0, (size_t)NN * NN * sizeof(float), stream);
    build_starts<<<1, 256, 0, stream>>>(batch, start);
    band_fill<<<NN, 64, 0, stream>>>(z1, z2, cls, batch, start, out);
}

// Round 5
// 646.649 us; speedup vs baseline: 1.0144x; 1.0144x over previous
//
#include <hip/hip_runtime.h>

#define NN 12288
#define DD 128

typedef float v4f __attribute__((ext_vector_type(4)));

// Fused single-pass kernel: one block per output row i, 256 threads.
// Thread t owns float4 chunks {t + 256*k : k=0..11}; each cell is written
// exactly once.
//
// FINAL (reverted to best measured variant, R0 = 644.4 us):
// R0-R4 falsified every structural lever on this problem:
//   - store-first ordering (R2), launch splitting (R1), boundary-table
//     precompute (R3), role-split grids (R3), vendor memset path (R4),
//     NT vs regular stores, XCD swizzle: all null to negative.
// The measured floor = mandatory 604 MB output write at the empirically
// achievable ~2.4-2.6 TB/s for this buffer + fixed harness poison-fill cost.
// This kernel sits on that floor.
__global__ __launch_bounds__(256) void segdec_fused(
    const float* __restrict__ z1, const float* __restrict__ z2,
    const int* __restrict__ cls, const int* __restrict__ batch,
    float* __restrict__ out)
{
    const int i   = blockIdx.x;
    const int tid = threadIdx.x;
    v4f* __restrict__ orow = reinterpret_cast<v4f*>(out + (size_t)i * NN);
    const v4f zero4 = {0.f, 0.f, 0.f, 0.f};

    const int cls_i = cls[i];
    if (cls_i >= 24) {
        // excluded class: whole row zero — pure nontemporal stream
        #pragma unroll
        for (int k = 0; k < 12; ++k)
            __builtin_nontemporal_store(zero4, &orow[tid + (k << 8)]);
        return;
    }

    // same-graph band [lo, hi): batch[] sorted -> binary search (block-uniform)
    const int batch_i = batch[i];
    int lo, hi;
    {
        int l = 0, r = NN;
        while (l < r) { int m = (l + r) >> 1; if (batch[m] <  batch_i) l = m + 1; else r = m; }
        lo = l;
        r = NN;
        while (l < r) { int m = (l + r) >> 1; if (batch[m] <= batch_i) l = m + 1; else r = m; }
        hi = l;
    }

    // Pass A: stream all non-band chunks (the overwhelming majority).
    unsigned band_mask = 0u;
    #pragma unroll
    for (int k = 0; k < 12; ++k) {
        const int f4 = tid + (k << 8);
        const int c0 = f4 << 2;
        if (c0 < hi && c0 + 4 > lo) {
            band_mask |= (1u << k);
        } else {
            __builtin_nontemporal_store(zero4, &orow[f4]);
        }
    }

    // Pass B: band chunks (~64 threads per block have exactly one).
    if (band_mask) {
        const v4f* __restrict__ za = reinterpret_cast<const v4f*>(z1 + (size_t)i * DD);
        while (band_mask) {
            const int k = __builtin_ctz(band_mask);
            band_mask &= band_mask - 1;
            const int f4 = tid + (k << 8);
            const int c0 = f4 << 2;
            float vv[4] = {0.f, 0.f, 0.f, 0.f};
            #pragma unroll
            for (int u = 0; u < 4; ++u) {
                const int j = c0 + u;
                if (j >= lo && j < hi && j != i && cls[j] == cls_i) {
                    const v4f* __restrict__ zb =
                        reinterpret_cast<const v4f*>(z2 + (size_t)j * DD);
                    float s = 0.f;
                    #pragma unroll
                    for (int d = 0; d < DD / 4; ++d) {
                        const v4f a = za[d];
                        const v4f b = zb[d];
                        s = fmaf(a.x, b.x, s);
                        s = fmaf(a.y, b.y, s);
                        s = fmaf(a.z, b.z, s);
                        s = fmaf(a.w, b.w, s);
                    }
                    vv[u] = s;
                }
            }
            const v4f v = {vv[0], vv[1], vv[2], vv[3]};
            __builtin_nontemporal_store(v, &orow[f4]);
        }
    }
}

extern "C" void kernel_launch(void* const* d_in, const int* in_sizes, int n_in,
                              void* d_out, int out_size, void* d_ws, size_t ws_size,
                              hipStream_t stream) {
    const float* z1    = (const float*)d_in[0];
    const float* z2    = (const float*)d_in[1];
    const int*   cls   = (const int*)d_in[2];
    const int*   batch = (const int*)d_in[3];
    float*       out   = (float*)d_out;

    segdec_fused<<<NN, 256, 0, stream>>>(z1, z2, cls, batch, out);
}